// Round 10
// baseline (45.496 us; speedup 1.0000x reference)
//
#include <hip/hip_runtime.h>

// K-manifold AE cluster objective, fused, bf16-MFMA GEMM.
// out = mean_b min_k [ ||x_b||^2 - 2 w.z + z^T G z + lamb*reg_k ]
// GEMM: Y[16384][320] = X[16384][512] @ W[512][320] via pre-packed B fragments.
// Round 10: B path via global_load_lds DMA (double-buffered, counted vmcnt,
// raw s_barrier) -- the m97/m201-proven staging structure.

#define KCLUST   16
#define DAMB     512
#define DLAT     10
#define BATCH    16384
#define LAMBDA   0.01f

#define BM       64            // batch rows per block (4 m-tiles)
#define NTHREADS 512           // 8 waves: 2M x 4N
#define NKS      16            // 512/32 k-steps
#define NNT      20            // 320/16 n-tiles
#define NBLK     (BATCH / BM)  // 256
#define CHB      40960         // bytes per B chunk (2 k-steps x 20 nt x 64 lanes x 16B)
#define SSTR     84            // epilogue strip stride (floats)

typedef __attribute__((ext_vector_type(8))) short short8;
typedef __attribute__((ext_vector_type(4))) float f32x4;

__device__ inline short f2bf(float f) {
    unsigned u = __builtin_bit_cast(unsigned, f);
    unsigned r = (u + 0x7FFFu + ((u >> 16) & 1u)) >> 16;
    return (short)r;
}

// ---------------- setup: blocks 0..79 pack W frags; 80..95 compute G/lreg; zero cnt
// wpack[ks][nt][lane][8]: lane l holds B[k = ks*32 + (l>>4)*8 + j][col = nt*16 + (l&15)]
__global__ __launch_bounds__(256) void setup_k(const float* __restrict__ Us,
                                               const float* __restrict__ Vs,
                                               short* __restrict__ wpack,
                                               float* __restrict__ G,
                                               float* __restrict__ lreg,
                                               unsigned* __restrict__ cnt) {
    int b = blockIdx.x;
    int tid = threadIdx.x;
    if (b == 0 && tid == 0)
        __hip_atomic_store(cnt, 0u, __ATOMIC_RELEASE, __HIP_MEMORY_SCOPE_AGENT);
    if (b < 80) {
        int idx  = b * 256 + tid;                  // [0, 16*20*64)
        int ks   = idx / (NNT * 64);
        int rem  = idx % (NNT * 64);
        int nt   = rem / 64;
        int lane = rem % 64;
        int col  = nt * 16 + (lane & 15);
        int cl   = col / 20;
        int c    = col % 20;
        short8 sv;
#pragma unroll
        for (int j = 0; j < 8; ++j) {
            int k = ks * 32 + (lane >> 4) * 8 + j;
            float v;
            if (c < DLAT) v = Vs[(size_t)cl * DLAT * DAMB + c * DAMB + k];
            else          v = Us[(size_t)cl * DAMB * DLAT + k * DLAT + (c - DLAT)];
            sv[j] = f2bf(v);
        }
        *(short8*)&wpack[(size_t)idx * 8] = sv;
    } else {
        __shared__ float red[256];
        int k = b - 80;
        const float* Uk = Us + (size_t)k * DAMB * DLAT;
        const float* Vk = Vs + (size_t)k * DLAT * DAMB;
        float s = 0.f;
        for (int i = tid; i < DAMB * DLAT; i += 256) {
            float a = Uk[i], bb = Vk[i];
            s += a * a + bb * bb;
        }
        red[tid] = s;
        __syncthreads();
        for (int st = 128; st > 0; st >>= 1) {
            if (tid < st) red[tid] += red[tid + st];
            __syncthreads();
        }
        if (tid == 0) lreg[k] = LAMBDA * 0.5f * red[0];
        if (tid < DLAT * DLAT) {
            int i = tid / DLAT, j = tid % DLAT;
            float g = 0.f;
            for (int Dv = 0; Dv < DAMB; ++Dv)
                g += Uk[Dv * DLAT + i] * Uk[Dv * DLAT + j];
            G[k * 100 + tid] = g;
        }
    }
}

__device__ __forceinline__ void gload_lds16(const void* g, void* l) {
    __builtin_amdgcn_global_load_lds(
        (const __attribute__((address_space(1))) unsigned int*)g,
        (__attribute__((address_space(3))) unsigned int*)l, 16, 0, 0);
}

template <int N> __device__ __forceinline__ void waitv() {
    if constexpr (N == 0)      asm volatile("s_waitcnt vmcnt(0)" ::: "memory");
    else if constexpr (N == 5) asm volatile("s_waitcnt vmcnt(5)" ::: "memory");
    __builtin_amdgcn_sched_barrier(0);   // rule #18
}

// ---------------- main kernel
__global__ __launch_bounds__(NTHREADS) void main_k(const float* __restrict__ x,
                                                   const short* __restrict__ wpack,
                                                   const float* __restrict__ G,
                                                   const float* __restrict__ lreg,
                                                   float* __restrict__ parts,
                                                   unsigned* __restrict__ cnt,
                                                   float* __restrict__ out) {
    __shared__ __align__(16) char a_region[65536];    // A frags; epilogue strips
    __shared__ __align__(16) char b_region[2 * CHB];  // B dbuf; epilogue objl
    __shared__ float Gs[KCLUST * 100];
    __shared__ float lregs[KCLUST];
    __shared__ float rsqp[BM][8];
    __shared__ float rowsq_s[BM];
    __shared__ int   isLast;

    short* a_lds = (short*)a_region;            // [mt 0..3][ks][lane][8]
    float* sbuf  = (float*)a_region;            // epilogue: [wv][16][SSTR]
    float (*objl)[17] = (float(*)[17])b_region; // epilogue: [64][17]

    const int tid  = threadIdx.x;
    const int lane = tid & 63;
    const int wv   = tid >> 6;                  // 0..7
    const int mw   = wv >> 2;                   // 0..1: m-tiles mw*2, mw*2+1
    const int nw   = wv & 3;                    // 0..3: n-tiles nw*5 .. +4
    const int row0 = blockIdx.x * BM;

    // ---- stage A (fp32 -> bf16, fragment order) + exact fp32 rowsq; stage G
    {
        const int srow = tid >> 3;              // 0..63
        const int sc   = tid & 7;
        const int mt   = srow >> 4;
        const int rlo  = srow & 15;
        const float* xr = x + (size_t)(row0 + srow) * DAMB;
        float rs = 0.f;
#pragma unroll
        for (int i = 0; i < 8; ++i) {
            int k8 = sc + 8 * i;                // 0..63
            float4 v0 = *(const float4*)(xr + k8 * 8);
            float4 v1 = *(const float4*)(xr + k8 * 8 + 4);
            rs += v0.x * v0.x + v0.y * v0.y + v0.z * v0.z + v0.w * v0.w
                + v1.x * v1.x + v1.y * v1.y + v1.z * v1.z + v1.w * v1.w;
            short8 sv;
            sv[0] = f2bf(v0.x); sv[1] = f2bf(v0.y); sv[2] = f2bf(v0.z); sv[3] = f2bf(v0.w);
            sv[4] = f2bf(v1.x); sv[5] = f2bf(v1.y); sv[6] = f2bf(v1.z); sv[7] = f2bf(v1.w);
            int ks = k8 >> 2, lh = k8 & 3;
            int ln = (lh << 4) | rlo;
            *(short8*)&a_lds[((mt * NKS + ks) * 64 + ln) * 8] = sv;
        }
        rsqp[srow][sc] = rs;
    }
    for (int i = tid; i < KCLUST * 100; i += NTHREADS) Gs[i] = G[i];
    if (tid < KCLUST) lregs[tid] = lreg[tid];
    __syncthreads();                 // full drain: vmcnt=0, clean counting base
    if (tid < BM) {
        float s = 0.f;
#pragma unroll
        for (int j = 0; j < 8; ++j) s += rsqp[tid][j];
        rowsq_s[tid] = s;
    }

    // ---- K loop: B chunks (2 k-steps) via global_load_lds DMA, double-buffered
    f32x4 acc[2][5];
#pragma unroll
    for (int m = 0; m < 2; ++m)
#pragma unroll
        for (int j = 0; j < 5; ++j) acc[m][j] = (f32x4)0.f;

    const char* wsrc = (const char*)wpack;
    const int soff = (wv * 5) * 1024 + lane * 16;   // this wave's slice in a chunk

#define ISSUE(c) do { \
        const char* s_ = wsrc + (size_t)(c) * CHB + soff; \
        char* d_ = b_region + ((c) & 1) * CHB + soff; \
        gload_lds16(s_ + 0,    d_ + 0); \
        gload_lds16(s_ + 1024, d_ + 1024); \
        gload_lds16(s_ + 2048, d_ + 2048); \
        gload_lds16(s_ + 3072, d_ + 3072); \
        gload_lds16(s_ + 4096, d_ + 4096); \
        __builtin_amdgcn_sched_barrier(0); \
    } while (0)

#define KSTEP(c, VM) do { \
        waitv<VM>(); \
        __builtin_amdgcn_s_barrier(); \
        __builtin_amdgcn_sched_barrier(0); \
        const short* B_ = (const short*)(b_region + ((c) & 1) * CHB); \
        _Pragma("unroll") \
        for (int ksl = 0; ksl < 2; ++ksl) { \
            short8 a0 = *(short8*)&a_lds[(((mw * 2 + 0) * NKS + (c) * 2 + ksl) * 64 + lane) * 8]; \
            short8 a1 = *(short8*)&a_lds[(((mw * 2 + 1) * NKS + (c) * 2 + ksl) * 64 + lane) * 8]; \
            _Pragma("unroll") \
            for (int j = 0; j < 5; ++j) { \
                short8 bf = *(short8*)&B_[((ksl * NNT + nw * 5 + j) * 64 + lane) * 8]; \
                acc[0][j] = __builtin_amdgcn_mfma_f32_16x16x32_bf16(a0, bf, acc[0][j], 0, 0, 0); \
                acc[1][j] = __builtin_amdgcn_mfma_f32_16x16x32_bf16(a1, bf, acc[1][j], 0, 0, 0); \
            } \
        } \
        __builtin_amdgcn_sched_barrier(0); \
        __builtin_amdgcn_s_barrier(); \
        __builtin_amdgcn_sched_barrier(0); \
    } while (0)

    ISSUE(0); ISSUE(1);
    KSTEP(0, 5); ISSUE(2);
    KSTEP(1, 5); ISSUE(3);
    KSTEP(2, 5); ISSUE(4);
    KSTEP(3, 5); ISSUE(5);
    KSTEP(4, 5); ISSUE(6);
    KSTEP(5, 5); ISSUE(7);
    KSTEP(6, 5);
    KSTEP(7, 0);

#undef KSTEP
#undef ISSUE

    // ---- epilogue: wave-local. Wave (mw,nw): rows mw*32..+31, clusters nw*4..+3.
    // Strip per wave aliases a_region; objl aliases b_region. C/D layout:
    // col = lane&15, row = (lane>>4)*4 + r.
    const int stro = wv * (16 * SSTR);
#pragma unroll
    for (int m = 0; m < 2; ++m) {               // m-tile = 16 rows
        int rowb = (lane >> 4) * 4;
#pragma unroll
        for (int j = 0; j < 5; ++j) {
            int colb = j * 16 + (lane & 15);
#pragma unroll
            for (int r = 0; r < 4; ++r)
                sbuf[stro + (rowb + r) * SSTR + colb] = acc[m][j][r];
        }
        // same-wave LDS RAW: in-order DS pipe + compiler lgkm waits; no barrier
        {
            int rowl = lane >> 2;               // 0..15
            int cl   = lane & 3;                // 0..3
            const float* yy = sbuf + stro + rowl * SSTR + cl * 20;
            float4 v0 = *(const float4*)(yy + 0);
            float4 v1 = *(const float4*)(yy + 4);
            float4 v2 = *(const float4*)(yy + 8);
            float4 v3 = *(const float4*)(yy + 12);
            float4 v4 = *(const float4*)(yy + 16);
            float z[DLAT] = {v0.x, v0.y, v0.z, v0.w, v1.x, v1.y, v1.z, v1.w, v2.x, v2.y};
            float w[DLAT] = {v2.z, v2.w, v3.x, v3.y, v3.z, v3.w, v4.x, v4.y, v4.z, v4.w};
            int kk = nw * 4 + cl;
            const float* Gk = Gs + kk * 100;
            float s = 0.f, wz = 0.f;
#pragma unroll
            for (int a = 0; a < DLAT; ++a) {
                float gz = 0.f;
#pragma unroll
                for (int b2 = 0; b2 < DLAT; ++b2) gz = fmaf(Gk[a * DLAT + b2], z[b2], gz);
                s  = fmaf(z[a], gz, s);
                wz = fmaf(w[a], z[a], wz);
            }
            objl[mw * 32 + m * 16 + rowl][kk] = s - 2.f * wz + lregs[kk];
        }
        __syncthreads();                        // strip reuse across m-tiles
    }

    // ---- per-row min + wave-0 shuffle reduce
    if (wv == 0) {
        float mn = objl[lane][0];
#pragma unroll
        for (int k = 1; k < KCLUST; ++k) mn = fminf(mn, objl[lane][k]);
        float v = mn + rowsq_s[lane];
#pragma unroll
        for (int off = 32; off > 0; off >>= 1) v += __shfl_down(v, off);
        if (lane == 0) {
            __hip_atomic_store(&parts[blockIdx.x], v, __ATOMIC_RELEASE,
                               __HIP_MEMORY_SCOPE_AGENT);
            unsigned prev = __hip_atomic_fetch_add(cnt, 1u, __ATOMIC_ACQ_REL,
                                                   __HIP_MEMORY_SCOPE_AGENT);
            isLast = (prev == NBLK - 1);
        }
    }
    __syncthreads();

    // ---- last block reduces all 256 partials (fixed-order => deterministic)
    if (isLast && wv == 0) {
        float s = 0.f;
#pragma unroll
        for (int q = 0; q < NBLK / 64; ++q)
            s += __hip_atomic_load(&parts[lane + q * 64], __ATOMIC_RELAXED,
                                   __HIP_MEMORY_SCOPE_AGENT);
#pragma unroll
        for (int off = 32; off > 0; off >>= 1) s += __shfl_down(s, off);
        if (lane == 0) out[0] = s * (1.0f / BATCH);
    }
}

extern "C" void kernel_launch(void* const* d_in, const int* in_sizes, int n_in,
                              void* d_out, int out_size, void* d_ws, size_t ws_size,
                              hipStream_t stream) {
    const float* x  = (const float*)d_in[0];   // 16384 x 512
    const float* Us = (const float*)d_in[1];   // 16 x 512 x 10
    const float* Vs = (const float*)d_in[2];   // 16 x 10 x 512
    float* out = (float*)d_out;

    // workspace: wpack[20480*8] shorts (320KB) | G[1600] | lreg[16] | parts[256] | cnt
    short* wpack   = (short*)d_ws;
    float* G       = (float*)(wpack + NKS * NNT * 64 * 8);
    float* lreg    = G + KCLUST * 100;
    float* parts   = lreg + KCLUST;
    unsigned* cnt  = (unsigned*)(parts + NBLK);

    setup_k<<<96, 256, 0, stream>>>(Us, Vs, wpack, G, lreg, cnt);
    main_k<<<NBLK, NTHREADS, 0, stream>>>(x, wpack, G, lreg, parts, cnt, out);
}